// Round 10
// baseline (53.675 us; speedup 1.0000x reference)
//
#include <hip/hip_runtime.h>
#include <hip/hip_fp16.h>

// NeRF hash-grid encode (5 levels) + 2 MLP heads.
// Round 13: 4-blocks/CU occupancy config. Base = round-11/12 passing text.
// Changes: (a) unpadded table strides (L0 32, L1 16, L2 8 halfs/row) — R12
// proved bank conflicts are off the critical path, so padding bought nothing;
// (b) wz epilogue block read from global (L2-hot) instead of LDS; LDS image
// is exactly 40960 B -> 4 blocks/CU * 8 waves = 32 waves/CU (hw cap) vs 24,
// with fine 8-wave barrier granularity (R9's regression used 16-wave blocks).
// launch_bounds(512,8) caps VGPR at 64. All arithmetic bit-identical.

#define NPTS 262144
#define BLOCK 512
#define PTS_PER_TILE 128    // 8 waves * 16 points
#define PTS_PER_BLOCK 256   // 2 tiles

// LDS/ws image layout (bytes): [tables 24576][wt frags 16384] = 40960
// ws-only tail: [wz 2048] at 40960
#define IMG_TAB   0
#define IMG_WTF   24576
#define IMG_BYTES 40960
#define IMG_WZ    40960

// table layout in f16 units (within IMG_TAB); unpadded strides
#define OFF_L0 0        // 50 x 32   (D=32, b128 reads, 64B row)
#define OFF_L1 1600     // 200 x 16  (D=16, b64 reads, 32B row)
#define OFF_L2 4800     // 400 x 8   (D=8,  b64 reads, 16B row)
#define OFF_L3 8000     // 400 x 4   (D=4,  b64 reads, 8B row)
#define OFF_L4 9600     // 400 x 4   (D=3+pad)
#define TAB_HALFS 12288 // used 11200, zero-padded to 24576 B region

typedef _Float16 f16x8 __attribute__((ext_vector_type(8)));
typedef _Float16 f16x4 __attribute__((ext_vector_type(4)));
typedef float f32x4 __attribute__((ext_vector_type(4)));

union AF { unsigned u[4]; f16x8 h; };

__device__ __forceinline__ void async_cp16(const void* g, void* l) {
    __builtin_amdgcn_global_load_lds(
        (__attribute__((address_space(1))) unsigned int*)const_cast<void*>(g),
        (__attribute__((address_space(3))) unsigned int*)l, 16, 0, 0);
}

__global__ void prep_kernel(const float* __restrict__ Wd1, const float* __restrict__ bd1,
                            const float* __restrict__ Wd2,
                            const float* __restrict__ Wc1, const float* __restrict__ bc1,
                            const float* __restrict__ Wc2,
                            const float* __restrict__ e0, const float* __restrict__ e1,
                            const float* __restrict__ e2, const float* __restrict__ e3,
                            const float* __restrict__ e4,
                            void* __restrict__ ws) {
    _Float16* tab = (_Float16*)((char*)ws + IMG_TAB);
    _Float16* wtf = (_Float16*)((char*)ws + IMG_WTF);
    float*    bw  = (float*)((char*)ws + IMG_WZ);
    const int gtid = blockIdx.x * blockDim.x + threadIdx.x;   // 64*256 = 16384
    const int gstr = gridDim.x * blockDim.x;

    // ---- W1cat^T as MFMA B-fragments, lane-consecutive chunk order ----
    // chunk i (f16x8): nt=i>>7, s=(i>>6)&1, l=i&63 (kq=l>>4, lo=l&15)
    // holds col = nt*16+lo, k = s*32 + kq*8 + j
    for (int i = gtid; i < 1024; i += gstr) {
        int nt = i >> 7, rem = i & 127, s = rem >> 6, l = rem & 63;
        int kq = l >> 4, lo = l & 15, col = nt * 16 + lo;
#pragma unroll
        for (int j = 0; j < 8; ++j) {
            int k = s * 32 + kq * 8 + j;
            float v = 0.f;
            if (k < 63) {
                if (col < 63) v = Wd1[k * 63 + col];
                else if (col >= 64 && col < 127) v = Wc1[k * 63 + (col - 64)];
            }
            wtf[i * 8 + j] = (_Float16)v;
        }
    }
    // ---- packed epilogue block (ws-only): float4 wz[col] = {bias,w2a,w2b,w2c}
    for (int i = gtid; i < 512; i += gstr) {
        int col = i >> 2, j = i & 3;
        float v = 0.f;
        if (j == 0) {
            if (col < 63) v = bd1[col];
            else if (col >= 64 && col < 127) v = bc1[col - 64];
        } else if (col < 64) {
            if (j == 1 && col < 63) v = Wd2[col];
        } else {
            int c2 = col - 64;
            if (c2 < 63) v = Wc2[c2 * 3 + (j - 1)];
        }
        bw[i] = v;
    }
    // ---- f16 tables, unpadded strides ----
    for (int idx = gtid; idx < 50 * 32; idx += gstr)
        tab[OFF_L0 + idx] = (_Float16)e0[idx];
    for (int idx = gtid; idx < 200 * 16; idx += gstr)
        tab[OFF_L1 + idx] = (_Float16)e1[idx];
    for (int idx = gtid; idx < 400 * 8; idx += gstr)
        tab[OFF_L2 + idx] = (_Float16)e2[idx];
    for (int idx = gtid; idx < 400 * 4; idx += gstr)
        tab[OFF_L3 + idx] = (_Float16)e3[idx];
    for (int idx = gtid; idx < 400 * 4; idx += gstr) {
        int r = idx >> 2, c = idx & 3;
        tab[OFF_L4 + idx] = (c < 3) ? (_Float16)e4[r * 3 + c] : (_Float16)0.f;
    }
    for (int idx = 11200 + gtid; idx < TAB_HALFS; idx += gstr)   // DMA pad tail
        tab[idx] = (_Float16)0.f;
}

// python-style v % H for H with 2^31 mod H == 48 (H in {50,200,400}).
// q = floor(vu / H) via shift + magic-25 (0x51EB851F, s=3: exact for all u32).
__device__ __forceinline__ int pymod(int v, int H, int sh) {
    unsigned vu = (unsigned)v ^ 0x80000000u;           // v + 2^31, exact
    unsigned q = __umulhi(vu >> sh, 0x51EB851Fu) >> 3; // floor(vu/H)
    int m = (int)(vu - q * (unsigned)H);               // vu mod H, in [0,H)
    int h = m - 48;                                    // (m - 2^31 mod H)
    return h < 0 ? h + H : h;
}

struct Corner {
    int ax0, ax1, ay0, ay1, az0, az1;
    float rx, ry, rz;
};
__device__ __forceinline__ Corner mkcorner(float px, float py, float pz) {
    Corner c;
    float fx = floorf(px), fy = floorf(py), fz = floorf(pz);
    c.rx = px - fx; c.ry = py - fy; c.rz = pz - fz;
    c.ax0 = (int)((unsigned)(int)fx * 73856093u);
    c.ax1 = (int)((unsigned)(int)ceilf(px) * 73856093u);
    c.ay0 = (int)((unsigned)(int)fy * 19349663u);
    c.ay1 = (int)((unsigned)(int)ceilf(py) * 19349663u);
    c.az0 = (int)((unsigned)(int)fz * 83492791u);
    c.az1 = (int)((unsigned)(int)ceilf(pz) * 83492791u);
    return c;
}

#define CXOR(C, cc) ((((cc) & 4) ? C.ax1 : C.ax0) ^ (((cc) & 2) ? C.ay1 : C.ay0) \
                   ^ (((cc) & 1) ? C.az1 : C.az0))
#define CW(C, cc) ((((cc) & 4) ? (1.f - C.rx) : C.rx) * \
                   (((cc) & 2) ? (1.f - C.ry) : C.ry) * \
                   (((cc) & 1) ? (1.f - C.rz) : C.rz))

// rotate-reduce over each 16-lane row via DPP (VALU pipe, no LDS traffic)
#define ROR_ADD(v, CTRL) { \
    int _t = __builtin_amdgcn_update_dpp(0, __float_as_int(v), (CTRL), 0xF, 0xF, true); \
    (v) += __int_as_float(_t); }
__device__ __forceinline__ float rowsum16(float v) {
    ROR_ADD(v, 0x121)   // row_ror:1
    ROR_ADD(v, 0x122)   // row_ror:2
    ROR_ADD(v, 0x124)   // row_ror:4
    ROR_ADD(v, 0x128)   // row_ror:8
    return v;
}

// ---- corners + 24 hash indices for one point ----
#define MK_HASHES(CA, CB, CBR, HA, H0, H1, X0, X1, X2)                         \
    Corner CA = mkcorner((X0), (X1), (X2));                                    \
    Corner CB = mkcorner((X0) * sA, (X1) * sA, (X2) * sA);                     \
    Corner CBR;                                                                \
    {                                                                          \
        const float dx_ = (X0) / 0.05f, dy_ = (X1) / 0.05f, dz_ = (X2) / 0.05f;\
        const float b1x_ = q3 ? dx_ : (X0) * sA;                               \
        const float b1y_ = q3 ? dy_ : (X1) * sA;                               \
        const float b1z_ = q3 ? dz_ : (X2) * sA;                               \
        CBR = mkcorner(b1x_, b1y_, b1z_);                                      \
    }                                                                          \
    int HA[8], H0[8], H1[8];                                                   \
    _Pragma("unroll")                                                          \
    for (int cc = 0; cc < 8; ++cc) HA[cc] = pymod(CXOR(CA, cc), 50, 1);        \
    _Pragma("unroll")                                                          \
    for (int cc = 0; cc < 8; ++cc) H0[cc] = pymod(CXOR(CB, cc), H, sh);        \
    _Pragma("unroll")                                                          \
    for (int cc = 0; cc < 8; ++cc) H1[cc] = pymod(CXOR(CBR, cc), H, sh);

// ---- front-end: gathers -> trilinear -> pack to A-fragments ----
#define FRONTEND(A0, A1, CA, CB, CBR, HA, H0, H1)                              \
{                                                                              \
    const int kq8 = kq * 8;                                                    \
    f16x8 va[8];                                                               \
    _Pragma("unroll")                                                          \
    for (int cc = 0; cc < 8; ++cc)                                             \
        va[cc] = *(const f16x8*)(ldsT + OFF_L0 + HA[cc] * 32 + kq8);           \
    f16x4 ea[8];                                                               \
    _Pragma("unroll")                                                          \
    for (int cc = 0; cc < 8; ++cc)                                             \
        ea[cc] = *(const f16x4*)(ldsT + tb0 + H0[cc] * st + fo0);              \
    float fA[8] = {0.f, 0.f, 0.f, 0.f, 0.f, 0.f, 0.f, 0.f};                    \
    _Pragma("unroll")                                                          \
    for (int cc = 0; cc < 8; ++cc) {                                           \
        float w = CW(CA, cc);                                                  \
        _Pragma("unroll")                                                      \
        for (int j = 0; j < 8; ++j)                                            \
            fA[j] = fmaf((float)va[cc][j], w, fA[j]);                          \
    }                                                                          \
    f16x4 eb[8];                                                               \
    _Pragma("unroll")                                                          \
    for (int cc = 0; cc < 8; ++cc)                                             \
        eb[cc] = *(const f16x4*)(ldsT + tb1 + H1[cc] * st + fo1);              \
    float fB[8] = {0.f, 0.f, 0.f, 0.f, 0.f, 0.f, 0.f, 0.f};                    \
    _Pragma("unroll")                                                          \
    for (int cc = 0; cc < 8; ++cc) {                                           \
        float w = CW(CB, cc);                                                  \
        fB[0] = fmaf((float)ea[cc][0], w, fB[0]);                              \
        fB[1] = fmaf((float)ea[cc][1], w, fB[1]);                              \
        fB[2] = fmaf((float)ea[cc][2], w, fB[2]);                              \
        fB[3] = fmaf((float)ea[cc][3], w, fB[3]);                              \
    }                                                                          \
    _Pragma("unroll")                                                          \
    for (int cc = 0; cc < 8; ++cc) {                                           \
        float w = CW(CBR, cc);                                                 \
        fB[4] = fmaf((float)eb[cc][0], w, fB[4]);                              \
        fB[5] = fmaf((float)eb[cc][1], w, fB[5]);                              \
        fB[6] = fmaf((float)eb[cc][2], w, fB[6]);                              \
        fB[7] = fmaf((float)eb[cc][3], w, fB[7]);                              \
    }                                                                          \
    if (q3) fB[7] = 0.f;                                                       \
    _Pragma("unroll")                                                          \
    for (int j = 0; j < 4; ++j) {                                              \
        __half2 t0 = __floats2half2_rn(fA[2 * j], fA[2 * j + 1]);              \
        __half2 t1 = __floats2half2_rn(fB[2 * j], fB[2 * j + 1]);              \
        A0.u[j] = *(unsigned*)&t0;                                             \
        A1.u[j] = *(unsigned*)&t1;                                             \
    }                                                                          \
}

#define REDUCE_STORE(PD, PX, PY, PZ, WB)                                       \
    _Pragma("unroll")                                                          \
    for (int r = 0; r < 4; ++r) {                                              \
        PD[r] = rowsum16(PD[r]); PX[r] = rowsum16(PX[r]);                      \
        PY[r] = rowsum16(PY[r]); PZ[r] = rowsum16(PZ[r]);                      \
    }                                                                          \
    if (lo < 4) {                                                              \
        float badd = (lo == 0) ? bd2v                                          \
                   : ((lo == 1) ? bcx : ((lo == 2) ? bcy : bcz));              \
        _Pragma("unroll")                                                      \
        for (int r = 0; r < 4; ++r) {                                          \
            int row = (WB) + kq * 4 + r;                                       \
            int addr = (lo == 0) ? row : (NPTS + row * 3 + (lo - 1));          \
            float v = (lo == 0) ? PD[r]                                        \
                    : ((lo == 1) ? PX[r] : ((lo == 2) ? PY[r] : PZ[r]));       \
            out[addr] = v + badd;                                              \
        }                                                                      \
    }

__global__ __launch_bounds__(BLOCK, 8) void nerf_fwd(
    const float* __restrict__ x,
    const float* __restrict__ bd2, const float* __restrict__ bc2,
    const void* __restrict__ ws,
    float* __restrict__ out)
{
    __shared__ __align__(16) char ldsb[IMG_BYTES];
    const int tid = threadIdx.x;

    // ---- stage 40 KiB image via 16B async DMA: 512 thr * 16B * 5 passes ----
    {
        const char* gsrc = (const char*)ws + tid * 16;
        char* ldst = ldsb + tid * 16;
#pragma unroll
        for (int i = 0; i < 5; ++i)
            async_cp16(gsrc + i * 8192, ldst + i * 8192);
    }

    const int l  = tid & 63;
    const int lo = l & 15;          // point-in-wave / MFMA row & col lane
    const int kq = l >> 4;          // k-chunk group 0..3
    const int wb0 = blockIdx.x * PTS_PER_BLOCK + (tid >> 6) * 16;   // tile 0
    const int wb1 = wb0 + PTS_PER_TILE;                             // tile 1

    // ======== DMA shadow: x loads (both tiles) + tile-0 hashes ========
    const int p0 = wb0 + lo, p1 = wb1 + lo;
    const float x00 = x[3 * p0 + 0], x01 = x[3 * p0 + 1], x02 = x[3 * p0 + 2];
    const float x10 = x[3 * p1 + 0], x11 = x[3 * p1 + 1], x12 = x[3 * p1 + 2];

    // per-kq part-B parameters
    const bool q2 = (kq == 2), q3 = (kq == 3);
    const int  g  = kq >> 1;
    const int  H  = 200 << g;           // 200,200,400,400
    const int  sh = 3 + g;
    const float sA = q3 ? 8.f : (q2 ? 4.f : 2.f);   // 1/vsl (exact pow2)
    const int tb0 = q3 ? OFF_L3 : (q2 ? OFF_L2 : OFF_L1);
    const int st  = q3 ? 4 : (q2 ? 8 : 16);         // f16 units (unpadded)
    const int fo0 = (kq == 1) ? 8 : 0;
    const int tb1 = q3 ? OFF_L4 : tb0;
    const int fo1 = q3 ? 0 : fo0 + 4;

    MK_HASHES(ca0, cb0, cr0, hA0, h00, h10, x00, x01, x02)

    // hoist uniform layer-2 biases (scalar loads, overlap DMA)
    const float bd2v = bd2[0];
    const float bcx = bc2[0], bcy = bc2[1], bcz = bc2[2];

    __syncthreads();   // drains vmcnt (DMA + x) before gathers

    const _Float16* ldsT = (const _Float16*)ldsb;
    const f16x8* wtf = (const f16x8*)(ldsb + IMG_WTF);
    const float4* wz = (const float4*)((const char*)ws + IMG_WZ);   // L2-hot

    // ---- tile-0 front-end ----
    AF a0A, a1A;
    FRONTEND(a0A, a1A, ca0, cb0, cr0, hA0, h00, h10)

    // ---- tile-1 hashes + front-end ----
    MK_HASHES(ca1, cb1, cr1, hA1, h01, h11, x10, x11, x12)
    AF a0B, a1B;
    FRONTEND(a0B, a1B, ca1, cb1, cr1, hA1, h01, h11)

    // ---- fused layer-1 MFMA: each weight fragment read once, 4 MFMAs ----
    float pd0[4]  = {0.f, 0.f, 0.f, 0.f}, pd1[4]  = {0.f, 0.f, 0.f, 0.f};
    float px0[4]  = {0.f, 0.f, 0.f, 0.f}, px1[4]  = {0.f, 0.f, 0.f, 0.f};
    float py0[4]  = {0.f, 0.f, 0.f, 0.f}, py1[4]  = {0.f, 0.f, 0.f, 0.f};
    float pz0[4]  = {0.f, 0.f, 0.f, 0.f}, pz1[4]  = {0.f, 0.f, 0.f, 0.f};

#pragma unroll
    for (int nt = 0; nt < 8; ++nt) {
        // lane-consecutive b128 reads: chunk (nt*2+s)*64 + l  (conflict-free)
        f16x8 b0 = wtf[(nt * 2 + 0) * 64 + l];
        f16x8 b1 = wtf[(nt * 2 + 1) * 64 + l];
        f32x4 c0 = {0.f, 0.f, 0.f, 0.f};
        f32x4 c1 = {0.f, 0.f, 0.f, 0.f};
        c0 = __builtin_amdgcn_mfma_f32_16x16x32_f16(a0A.h, b0, c0, 0, 0, 0);
        c0 = __builtin_amdgcn_mfma_f32_16x16x32_f16(a1A.h, b1, c0, 0, 0, 0);
        c1 = __builtin_amdgcn_mfma_f32_16x16x32_f16(a0B.h, b0, c1, 0, 0, 0);
        c1 = __builtin_amdgcn_mfma_f32_16x16x32_f16(a1B.h, b1, c1, 0, 0, 0);
        float4 z = wz[nt * 16 + lo];     // {bias, w2a, w2b, w2c}, one b128
        if (nt < 4) {
#pragma unroll
            for (int r = 0; r < 4; ++r) {
                pd0[r] = fmaf(fmaxf(c0[r] + z.x, 0.f), z.y, pd0[r]);
                pd1[r] = fmaf(fmaxf(c1[r] + z.x, 0.f), z.y, pd1[r]);
            }
        } else {
#pragma unroll
            for (int r = 0; r < 4; ++r) {
                float t0 = fmaxf(c0[r] + z.x, 0.f);
                float t1 = fmaxf(c1[r] + z.x, 0.f);
                px0[r] = fmaf(t0, z.y, px0[r]); py0[r] = fmaf(t0, z.z, py0[r]);
                pz0[r] = fmaf(t0, z.w, pz0[r]);
                px1[r] = fmaf(t1, z.y, px1[r]); py1[r] = fmaf(t1, z.z, py1[r]);
                pz1[r] = fmaf(t1, z.w, pz1[r]);
            }
        }
    }

    // ---- per-tile DPP reduce + store ----
    REDUCE_STORE(pd0, px0, py0, pz0, wb0)
    REDUCE_STORE(pd1, px1, py1, pz1, wb1)
}

extern "C" void kernel_launch(void* const* d_in, const int* in_sizes, int n_in,
                              void* d_out, int out_size, void* d_ws, size_t ws_size,
                              hipStream_t stream) {
    const float* x   = (const float*)d_in[0];
    const float* e0  = (const float*)d_in[1];
    const float* e1  = (const float*)d_in[2];
    const float* e2  = (const float*)d_in[3];
    const float* e3  = (const float*)d_in[4];
    const float* e4  = (const float*)d_in[5];
    const float* Wd1 = (const float*)d_in[6];
    const float* bd1 = (const float*)d_in[7];
    const float* Wd2 = (const float*)d_in[8];
    const float* bd2 = (const float*)d_in[9];
    const float* Wc1 = (const float*)d_in[10];
    const float* bc1 = (const float*)d_in[11];
    const float* Wc2 = (const float*)d_in[12];
    const float* bc2 = (const float*)d_in[13];
    float* out = (float*)d_out;

    prep_kernel<<<64, 256, 0, stream>>>(Wd1, bd1, Wd2, Wc1, bc1, Wc2,
                                        e0, e1, e2, e3, e4, d_ws);
    nerf_fwd<<<dim3(NPTS / PTS_PER_BLOCK), dim3(BLOCK), 0, stream>>>(
        x, bd2, bc2, d_ws, out);
}

// Round 11
// 35.918 us; speedup vs baseline: 1.4944x; 1.4944x over previous
//
#include <hip/hip_runtime.h>
#include <hip/hip_fp16.h>

// NeRF hash-grid encode (5 levels) + 2 MLP heads.
// Round 14: clean 4-blocks/CU test. R13's regression was SPILL (WRITE_SIZE
// 122MB = scratch), not occupancy: launch_bounds(512,8) vs a ~100-VGPR fused
// body. This round: single-tile body (36 VGPR in R4/R7, fits the 64-VGPR
// 8-wave budget) + 40960B LDS image -> 4 blocks/CU * 8 waves = 32 waves/CU
// at fine 8-wave barrier granularity. wz epilogue block read from global
// (L2-hot). All arithmetic bit-identical to the 36-us plateau kernels.

#define NPTS 262144
#define BLOCK 512
#define PTS_PER_BLOCK 128   // 8 waves * 16 points, single tile

// LDS/ws image layout (bytes): [tables 24576][wt frags 16384] = 40960
// ws-only tail: [wz 2048] at 40960
#define IMG_TAB   0
#define IMG_WTF   24576
#define IMG_BYTES 40960
#define IMG_WZ    40960

// table layout in f16 units (within IMG_TAB); unpadded strides
#define OFF_L0 0        // 50 x 32   (D=32, b128 reads, 64B row)
#define OFF_L1 1600     // 200 x 16  (D=16, b64 reads, 32B row)
#define OFF_L2 4800     // 400 x 8   (D=8,  b64 reads, 16B row)
#define OFF_L3 8000     // 400 x 4   (D=4,  b64 reads, 8B row)
#define OFF_L4 9600     // 400 x 4   (D=3+pad)
#define TAB_HALFS 12288 // used 11200, zero-padded to 24576 B region

typedef _Float16 f16x8 __attribute__((ext_vector_type(8)));
typedef _Float16 f16x4 __attribute__((ext_vector_type(4)));
typedef float f32x4 __attribute__((ext_vector_type(4)));

union AF { unsigned u[4]; f16x8 h; };

__device__ __forceinline__ void async_cp16(const void* g, void* l) {
    __builtin_amdgcn_global_load_lds(
        (__attribute__((address_space(1))) unsigned int*)const_cast<void*>(g),
        (__attribute__((address_space(3))) unsigned int*)l, 16, 0, 0);
}

__global__ void prep_kernel(const float* __restrict__ Wd1, const float* __restrict__ bd1,
                            const float* __restrict__ Wd2,
                            const float* __restrict__ Wc1, const float* __restrict__ bc1,
                            const float* __restrict__ Wc2,
                            const float* __restrict__ e0, const float* __restrict__ e1,
                            const float* __restrict__ e2, const float* __restrict__ e3,
                            const float* __restrict__ e4,
                            void* __restrict__ ws) {
    _Float16* tab = (_Float16*)((char*)ws + IMG_TAB);
    _Float16* wtf = (_Float16*)((char*)ws + IMG_WTF);
    float*    bw  = (float*)((char*)ws + IMG_WZ);
    const int gtid = blockIdx.x * blockDim.x + threadIdx.x;   // 64*256 = 16384
    const int gstr = gridDim.x * blockDim.x;

    // ---- W1cat^T as MFMA B-fragments, lane-consecutive chunk order ----
    // chunk i (f16x8): nt=i>>7, s=(i>>6)&1, l=i&63 (kq=l>>4, lo=l&15)
    // holds col = nt*16+lo, k = s*32 + kq*8 + j
    for (int i = gtid; i < 1024; i += gstr) {
        int nt = i >> 7, rem = i & 127, s = rem >> 6, l = rem & 63;
        int kq = l >> 4, lo = l & 15, col = nt * 16 + lo;
#pragma unroll
        for (int j = 0; j < 8; ++j) {
            int k = s * 32 + kq * 8 + j;
            float v = 0.f;
            if (k < 63) {
                if (col < 63) v = Wd1[k * 63 + col];
                else if (col >= 64 && col < 127) v = Wc1[k * 63 + (col - 64)];
            }
            wtf[i * 8 + j] = (_Float16)v;
        }
    }
    // ---- packed epilogue block (ws-only): float4 wz[col] = {bias,w2a,w2b,w2c}
    for (int i = gtid; i < 512; i += gstr) {
        int col = i >> 2, j = i & 3;
        float v = 0.f;
        if (j == 0) {
            if (col < 63) v = bd1[col];
            else if (col >= 64 && col < 127) v = bc1[col - 64];
        } else if (col < 64) {
            if (j == 1 && col < 63) v = Wd2[col];
        } else {
            int c2 = col - 64;
            if (c2 < 63) v = Wc2[c2 * 3 + (j - 1)];
        }
        bw[i] = v;
    }
    // ---- f16 tables, unpadded strides ----
    for (int idx = gtid; idx < 50 * 32; idx += gstr)
        tab[OFF_L0 + idx] = (_Float16)e0[idx];
    for (int idx = gtid; idx < 200 * 16; idx += gstr)
        tab[OFF_L1 + idx] = (_Float16)e1[idx];
    for (int idx = gtid; idx < 400 * 8; idx += gstr)
        tab[OFF_L2 + idx] = (_Float16)e2[idx];
    for (int idx = gtid; idx < 400 * 4; idx += gstr)
        tab[OFF_L3 + idx] = (_Float16)e3[idx];
    for (int idx = gtid; idx < 400 * 4; idx += gstr) {
        int r = idx >> 2, c = idx & 3;
        tab[OFF_L4 + idx] = (c < 3) ? (_Float16)e4[r * 3 + c] : (_Float16)0.f;
    }
    for (int idx = 11200 + gtid; idx < TAB_HALFS; idx += gstr)   // DMA pad tail
        tab[idx] = (_Float16)0.f;
}

// python-style v % H for H with 2^31 mod H == 48 (H in {50,200,400}).
// q = floor(vu / H) via shift + magic-25 (0x51EB851F, s=3: exact for all u32).
__device__ __forceinline__ int pymod(int v, int H, int sh) {
    unsigned vu = (unsigned)v ^ 0x80000000u;           // v + 2^31, exact
    unsigned q = __umulhi(vu >> sh, 0x51EB851Fu) >> 3; // floor(vu/H)
    int m = (int)(vu - q * (unsigned)H);               // vu mod H, in [0,H)
    int h = m - 48;                                    // (m - 2^31 mod H)
    return h < 0 ? h + H : h;
}

struct Corner {
    int ax0, ax1, ay0, ay1, az0, az1;
    float rx, ry, rz;
};
__device__ __forceinline__ Corner mkcorner(float px, float py, float pz) {
    Corner c;
    float fx = floorf(px), fy = floorf(py), fz = floorf(pz);
    c.rx = px - fx; c.ry = py - fy; c.rz = pz - fz;
    c.ax0 = (int)((unsigned)(int)fx * 73856093u);
    c.ax1 = (int)((unsigned)(int)ceilf(px) * 73856093u);
    c.ay0 = (int)((unsigned)(int)fy * 19349663u);
    c.ay1 = (int)((unsigned)(int)ceilf(py) * 19349663u);
    c.az0 = (int)((unsigned)(int)fz * 83492791u);
    c.az1 = (int)((unsigned)(int)ceilf(pz) * 83492791u);
    return c;
}

#define CXOR(C, cc) ((((cc) & 4) ? C.ax1 : C.ax0) ^ (((cc) & 2) ? C.ay1 : C.ay0) \
                   ^ (((cc) & 1) ? C.az1 : C.az0))
#define CW(C, cc) ((((cc) & 4) ? (1.f - C.rx) : C.rx) * \
                   (((cc) & 2) ? (1.f - C.ry) : C.ry) * \
                   (((cc) & 1) ? (1.f - C.rz) : C.rz))

// rotate-reduce over each 16-lane row via DPP (VALU pipe, no LDS traffic)
#define ROR_ADD(v, CTRL) { \
    int _t = __builtin_amdgcn_update_dpp(0, __float_as_int(v), (CTRL), 0xF, 0xF, true); \
    (v) += __int_as_float(_t); }
__device__ __forceinline__ float rowsum16(float v) {
    ROR_ADD(v, 0x121)   // row_ror:1
    ROR_ADD(v, 0x122)   // row_ror:2
    ROR_ADD(v, 0x124)   // row_ror:4
    ROR_ADD(v, 0x128)   // row_ror:8
    return v;
}

__global__ __launch_bounds__(BLOCK, 8) void nerf_fwd(
    const float* __restrict__ x,
    const float* __restrict__ bd2, const float* __restrict__ bc2,
    const void* __restrict__ ws,
    float* __restrict__ out)
{
    __shared__ __align__(16) char ldsb[IMG_BYTES];
    const int tid = threadIdx.x;

    // ---- stage 40 KiB image via 16B async DMA: 512 thr * 16B * 5 passes ----
    {
        const char* gsrc = (const char*)ws + tid * 16;
        char* ldst = ldsb + tid * 16;
#pragma unroll
        for (int i = 0; i < 5; ++i)
            async_cp16(gsrc + i * 8192, ldst + i * 8192);
    }

    const int l  = tid & 63;
    const int lo = l & 15;          // point-in-wave / MFMA row & col lane
    const int kq = l >> 4;          // k-chunk group 0..3
    const int wb = blockIdx.x * PTS_PER_BLOCK + (tid >> 6) * 16;
    const int p  = wb + lo;         // this lane's point

    // ======== everything address-generating runs in the DMA shadow ========
    const float x0 = x[3 * p + 0], x1 = x[3 * p + 1], x2 = x[3 * p + 2];

    // per-kq part-B parameters
    const bool q2 = (kq == 2), q3 = (kq == 3);
    const int  g  = kq >> 1;
    const int  H  = 200 << g;           // 200,200,400,400
    const int  sh = 3 + g;
    const float sA = q3 ? 8.f : (q2 ? 4.f : 2.f);   // 1/vsl (exact pow2)
    const int tb0 = q3 ? OFF_L3 : (q2 ? OFF_L2 : OFF_L1);
    const int st  = q3 ? 4 : (q2 ? 8 : 16);         // f16 units (unpadded)
    const int fo0 = (kq == 1) ? 8 : 0;
    const int tb1 = q3 ? OFF_L4 : tb0;
    const int fo1 = q3 ? 0 : fo0 + 4;

    // ---- corners + hashes (pure VALU, overlaps DMA) ----
    Corner ca = mkcorner(x0, x1, x2);               // L0, vsl = 1.0
    Corner cb = mkcorner(x0 * sA, x1 * sA, x2 * sA);
    Corner cb1;   // round-1 corner (L4 for kq3 via IEEE div, else same level)
    {
        const float dx = x0 / 0.05f, dy = x1 / 0.05f, dz = x2 / 0.05f;
        const float b1x = q3 ? dx : x0 * sA, b1y = q3 ? dy : x1 * sA,
                    b1z = q3 ? dz : x2 * sA;
        cb1 = mkcorner(b1x, b1y, b1z);
    }
    int hA[8], h0[8], h1[8];
#pragma unroll
    for (int cc = 0; cc < 8; ++cc) hA[cc] = pymod(CXOR(ca, cc), 50, 1);
#pragma unroll
    for (int cc = 0; cc < 8; ++cc) h0[cc] = pymod(CXOR(cb, cc), H, sh);
#pragma unroll
    for (int cc = 0; cc < 8; ++cc) h1[cc] = pymod(CXOR(cb1, cc), H, sh);

    // hoist uniform layer-2 biases (scalar loads, overlap DMA)
    const float bd2v = bd2[0];
    const float bcx = bc2[0], bcy = bc2[1], bcz = bc2[2];

    __syncthreads();   // drains vmcnt (DMA + x) before gathers

    const _Float16* ldsT = (const _Float16*)ldsb;
    const f16x8* wtf = (const f16x8*)(ldsb + IMG_WTF);
    const float4* wz = (const float4*)((const char*)ws + IMG_WZ);   // L2-hot

    // ======== batch-issue all gathers: deep LDS pipeline ========
    const int kq8 = kq * 8;
    f16x8 va[8];
#pragma unroll
    for (int cc = 0; cc < 8; ++cc)
        va[cc] = *(const f16x8*)(ldsT + OFF_L0 + hA[cc] * 32 + kq8);  // 16B aligned
    f16x4 ea[8];
#pragma unroll
    for (int cc = 0; cc < 8; ++cc)
        ea[cc] = *(const f16x4*)(ldsT + tb0 + h0[cc] * st + fo0);     // 8B aligned

    // part A FMAs (covers round-1 load latency below)
    float fA[8] = {0.f, 0.f, 0.f, 0.f, 0.f, 0.f, 0.f, 0.f};
#pragma unroll
    for (int cc = 0; cc < 8; ++cc) {
        float w = CW(ca, cc);
#pragma unroll
        for (int j = 0; j < 8; ++j)
            fA[j] = fmaf((float)va[cc][j], w, fA[j]);   // v_fma_mix_f32
    }

    f16x4 eb[8];
#pragma unroll
    for (int cc = 0; cc < 8; ++cc)
        eb[cc] = *(const f16x4*)(ldsT + tb1 + h1[cc] * st + fo1);

    float fB[8] = {0.f, 0.f, 0.f, 0.f, 0.f, 0.f, 0.f, 0.f};
#pragma unroll
    for (int cc = 0; cc < 8; ++cc) {
        float w = CW(cb, cc);
        fB[0] = fmaf((float)ea[cc][0], w, fB[0]); fB[1] = fmaf((float)ea[cc][1], w, fB[1]);
        fB[2] = fmaf((float)ea[cc][2], w, fB[2]); fB[3] = fmaf((float)ea[cc][3], w, fB[3]);
    }
#pragma unroll
    for (int cc = 0; cc < 8; ++cc) {
        float w = CW(cb1, cc);
        fB[4] = fmaf((float)eb[cc][0], w, fB[4]); fB[5] = fmaf((float)eb[cc][1], w, fB[5]);
        fB[6] = fmaf((float)eb[cc][2], w, fB[6]); fB[7] = fmaf((float)eb[cc][3], w, fB[7]);
    }
    if (q3) fB[7] = 0.f;   // k=63 pad (Wt row 63 is zero anyway)

    // ---- pack to f16 A-fragments (RTN) ----
    AF a0, a1;
#pragma unroll
    for (int j = 0; j < 4; ++j) {
        __half2 t0 = __floats2half2_rn(fA[2 * j], fA[2 * j + 1]);
        __half2 t1 = __floats2half2_rn(fB[2 * j], fB[2 * j + 1]);
        a0.u[j] = *(unsigned*)&t0;
        a1.u[j] = *(unsigned*)&t1;
    }

    // ---- layer 1 (fused dense+color) via MFMA, layer 2 partials ----
    float pd[4]  = {0.f, 0.f, 0.f, 0.f};
    float px[4]  = {0.f, 0.f, 0.f, 0.f};
    float py[4]  = {0.f, 0.f, 0.f, 0.f};
    float pz[4]  = {0.f, 0.f, 0.f, 0.f};

#pragma unroll
    for (int nt = 0; nt < 8; ++nt) {
        // lane-consecutive b128 reads: chunk (nt*2+s)*64 + l  (conflict-free)
        f16x8 b0 = wtf[(nt * 2 + 0) * 64 + l];
        f16x8 b1 = wtf[(nt * 2 + 1) * 64 + l];
        f32x4 c = {0.f, 0.f, 0.f, 0.f};
        c = __builtin_amdgcn_mfma_f32_16x16x32_f16(a0.h, b0, c, 0, 0, 0);
        c = __builtin_amdgcn_mfma_f32_16x16x32_f16(a1.h, b1, c, 0, 0, 0);
        float4 z = wz[nt * 16 + lo];     // {bias, w2a, w2b, w2c}, one 16B load
        if (nt < 4) {
#pragma unroll
            for (int r = 0; r < 4; ++r)
                pd[r] = fmaf(fmaxf(c[r] + z.x, 0.f), z.y, pd[r]);
        } else {
#pragma unroll
            for (int r = 0; r < 4; ++r) {
                float t = fmaxf(c[r] + z.x, 0.f);
                px[r] = fmaf(t, z.y, px[r]);
                py[r] = fmaf(t, z.z, py[r]);
                pz[r] = fmaf(t, z.w, pz[r]);
            }
        }
    }

    // ---- reduce over the 16 column-lanes via DPP rotate (VALU pipe) ----
#pragma unroll
    for (int r = 0; r < 4; ++r) {
        pd[r] = rowsum16(pd[r]);
        px[r] = rowsum16(px[r]);
        py[r] = rowsum16(py[r]);
        pz[r] = rowsum16(pz[r]);
    }

    // ---- merged store: lanes lo=0..3 each own one output channel ----
    if (lo < 4) {
        float badd = (lo == 0) ? bd2v : ((lo == 1) ? bcx : ((lo == 2) ? bcy : bcz));
#pragma unroll
        for (int r = 0; r < 4; ++r) {
            int row = wb + kq * 4 + r;
            int addr = (lo == 0) ? row : (NPTS + row * 3 + (lo - 1));
            float v = (lo == 0) ? pd[r]
                    : ((lo == 1) ? px[r] : ((lo == 2) ? py[r] : pz[r]));
            out[addr] = v + badd;
        }
    }
}

extern "C" void kernel_launch(void* const* d_in, const int* in_sizes, int n_in,
                              void* d_out, int out_size, void* d_ws, size_t ws_size,
                              hipStream_t stream) {
    const float* x   = (const float*)d_in[0];
    const float* e0  = (const float*)d_in[1];
    const float* e1  = (const float*)d_in[2];
    const float* e2  = (const float*)d_in[3];
    const float* e3  = (const float*)d_in[4];
    const float* e4  = (const float*)d_in[5];
    const float* Wd1 = (const float*)d_in[6];
    const float* bd1 = (const float*)d_in[7];
    const float* Wd2 = (const float*)d_in[8];
    const float* bd2 = (const float*)d_in[9];
    const float* Wc1 = (const float*)d_in[10];
    const float* bc1 = (const float*)d_in[11];
    const float* Wc2 = (const float*)d_in[12];
    const float* bc2 = (const float*)d_in[13];
    float* out = (float*)d_out;

    prep_kernel<<<64, 256, 0, stream>>>(Wd1, bd1, Wd2, Wc1, bc1, Wc2,
                                        e0, e1, e2, e3, e4, d_ws);
    nerf_fwd<<<dim3(NPTS / PTS_PER_BLOCK), dim3(BLOCK), 0, stream>>>(
        x, bd2, bc2, d_ws, out);
}